// Round 9
// baseline (211.501 us; speedup 1.0000x reference)
//
#include <hip/hip_runtime.h>
#include <cstddef>

#define BB 4
#define SS 2048
#define DMOD 32
#define AEL (BB*SS*DMOD)            // 262144 floats per projection array
#define WS_PROJ 16                  // reserved header
#define MB0 (WS_PROJ + 8*AEL)       // pmask (u64 x MWORDS) then nmask
#define MWORDS (BB*32*SS)           // 262144 u64 per mask
#define PART0 (MB0 + 4*MWORDS)      // float offset of partials
#define PSLOT (36*8192)             // floats per (pn, chunk) partial slot
#define TINY 1e-30f

__device__ __forceinline__ float fexp2(float x) {
#if defined(__has_builtin)
#if __has_builtin(__builtin_amdgcn_exp2f)
    return __builtin_amdgcn_exp2f(x);
#else
    return exp2f(x);
#endif
#else
    return exp2f(x);
#endif
}

// ---------- kernel 1: all 8 projections ----------
// mats: 0 q_o (raw), 1 k_o, 2 q_p (log2e/sqrt8), 3 k_p, 4 v_p,
//       5 q_n (log2e/sqrt8), 6 k_n, 7 v_n
__global__ __launch_bounds__(256) void k1_proj(
    const float* __restrict__ feat,
    const float* __restrict__ qw, const float* __restrict__ qb,
    const float* __restrict__ kw, const float* __restrict__ kb,
    const float* __restrict__ paw, const float* __restrict__ pab,
    const float* __restrict__ naw, const float* __restrict__ nab,
    float* __restrict__ wsf) {
    int g = blockIdx.x * 256 + threadIdx.x;
    int d4  = g & 7;
    int mat = (g >> 3) & 7;
    int row = g >> 6;
    const float* W; const float* Bv; float sc = 1.f;
    switch (mat) {
        case 0: W = qw;        Bv = qb;       break;
        case 1: W = kw;        Bv = kb;       break;
        case 2: W = paw;       Bv = pab;      sc = 0.5101370246954918f; break;
        case 3: W = paw+1024;  Bv = pab+32;   break;
        case 4: W = paw+2048;  Bv = pab+64;   break;
        case 5: W = naw;       Bv = nab;      sc = 0.5101370246954918f; break;
        case 6: W = naw+1024;  Bv = nab+32;   break;
        default:W = naw+2048;  Bv = nab+64;   break;
    }
    const float* fr = feat + row * DMOD;
    int o0 = d4 * 4;
    float acc[4];
    #pragma unroll
    for (int i = 0; i < 4; i++) acc[i] = Bv[o0+i];
    #pragma unroll
    for (int d = 0; d < DMOD; d++) {
        float fv = fr[d];
        #pragma unroll
        for (int i = 0; i < 4; i++) acc[i] += fv * W[(o0+i)*DMOD + d];
    }
    #pragma unroll
    for (int i = 0; i < 4; i++) acc[i] *= sc;
    float4 r = make_float4(acc[0], acc[1], acc[2], acc[3]);
    *(float4*)(wsf + WS_PROJ + (size_t)mat*AEL + (size_t)row*DMOD + o0) = r;
}

// ---------- kernel A: fused-score sign bits -> packed p/n masks ----------
// grid (jt=8, rt=32, b=4), block 256 = 4 waves x 64 lanes (lane = j offset)
// proj (read-only) and pmout (write-only) are DISTINCT restrict roots so the
// mask stores cannot serialize the dmask/q load pipeline.
__global__ __launch_bounds__(256) void kA_mask(
    const float* __restrict__ dmask, const float* __restrict__ proj,
    unsigned long long* __restrict__ pmout,
    const float* __restrict__ f1w, const float* __restrict__ f1b,
    const float* __restrict__ f2w, const float* __restrict__ f2b,
    const float* __restrict__ f3w, const float* __restrict__ f3b) {
    int tid = threadIdx.x;
    int w = tid >> 6, lane = tid & 63;
    int jt = blockIdx.x, rt = blockIdx.y, b = blockIdx.z;
    int jg = jt * 256 + w * 64 + lane;          // batch-local j

    // collapse conv stack: c_h = (1/sqrt8) * sum_a f3[a] sum_b f2[a,b] f1[b,h]
    float cc[4];
    #pragma unroll
    for (int h = 0; h < 4; h++) {
        float s = 0.f;
        #pragma unroll
        for (int a = 0; a < 4; a++) {
            float t = 0.f;
            #pragma unroll
            for (int bb = 0; bb < 8; bb++) t += f2w[a*8+bb] * f1w[bb*4+h];
            s += f3w[a] * t;
        }
        cc[h] = s * 0.35355339059327373f;
    }
    float cbv = f3b[0];
    #pragma unroll
    for (int a = 0; a < 4; a++) {
        float t = f2b[a];
        #pragma unroll
        for (int bb = 0; bb < 8; bb++) t += f2w[a*8+bb] * f1b[bb];
        cbv += f3w[a] * t;
    }

    const float* KOb = proj + WS_PROJ + 1*(size_t)AEL + ((size_t)b*SS + jg) * DMOD;
    float ko[32];
    #pragma unroll
    for (int i = 0; i < 8; i++) {
        float4 v = *(const float4*)(KOb + 4*i);
        ko[4*i] = v.x; ko[4*i+1] = v.y; ko[4*i+2] = v.z; ko[4*i+3] = v.w;
    }
    const float* QOb = proj + WS_PROJ + 0*(size_t)AEL + (size_t)b*SS*DMOD;
    unsigned long long* pm = pmout;
    unsigned long long* nm = pmout + MWORDS;
    const float* dmr = dmask + (size_t)b * SS * SS + jg;
    int j64 = jt * 4 + w;
    size_t mbase = ((size_t)b * 32 + j64) * SS;
    #pragma unroll 8
    for (int r = 0; r < 64; r++) {
        int row = rt * 64 + r;
        const float* qr = QOb + (size_t)row * DMOD;
        float dm = dmr[(size_t)row * SS];
        float fa = 0.f, fb = 0.f, fc = 0.f, fd = 0.f;   // per-head raw dots
        #pragma unroll
        for (int d = 0; d < 8; d++) {
            fa += qr[d]      * ko[d];
            fb += qr[8 + d]  * ko[8 + d];
            fc += qr[16 + d] * ko[16 + d];
            fd += qr[24 + d] * ko[24 + d];
        }
        float fused = cbv + cc[0]*fa + cc[1]*fb + cc[2]*fc + cc[3]*fd;
        bool act = (dm != 0.0f);
        unsigned long long bp = __ballot(act && (fused > 0.0f));
        unsigned long long bn = __ballot(act && !(fused > 0.0f));
        if (lane == 0) {
            pm[mbase + row] = bp;
            nm[mbase + row] = bn;
        }
    }
}

// ---------- kernel B: masked attention (p or n), split-K, LDS-staged K/V ----------
// grid (jc=NCH, rt=8, z=8: b=z>>1, pn=z&1), block 256 = 256 rows (all 4 heads)
__global__ __launch_bounds__(256) void kB_attn(
    const float* __restrict__ wsf_c, float* __restrict__ wsf, int CJ) {
    __shared__ float kls[64 * 32];   // 8 KB: K rows for current 64-j window
    __shared__ float vls[64 * 32];   // 8 KB: V rows
    int tid = threadIdx.x;
    int jc = blockIdx.x, rt = blockIdx.y;
    int b = blockIdx.z >> 1, pn = blockIdx.z & 1;
    int row = rt * 256 + tid;
    size_t grow = (size_t)b * SS + row;

    int qm = pn ? 5 : 2, km = pn ? 6 : 3, vm = pn ? 7 : 4;
    const float* Qb = wsf_c + WS_PROJ + (size_t)qm*AEL + grow*DMOD;
    const float* Kb = wsf_c + WS_PROJ + (size_t)km*AEL + (size_t)b*SS*DMOD;
    const float* Vb = wsf_c + WS_PROJ + (size_t)vm*AEL + (size_t)b*SS*DMOD;
    const unsigned long long* msk =
        (const unsigned long long*)(wsf_c + MB0) + (size_t)pn * MWORDS;

    float ql[32];
    #pragma unroll
    for (int i = 0; i < 8; i++) {
        float4 v = *(const float4*)(Qb + 4*i);
        ql[4*i] = v.x; ql[4*i+1] = v.y; ql[4*i+2] = v.z; ql[4*i+3] = v.w;
    }
    float a[32];
    #pragma unroll
    for (int i = 0; i < 32; i++) a[i] = 0.f;
    float l[4] = {0.f, 0.f, 0.f, 0.f};

    int jA0 = jc * CJ;
    for (int j0 = 0; j0 < CJ; j0 += 64) {
        int jA = jA0 + j0;
        // cooperative stage: 64 K-rows + 64 V-rows (2 x 8 KB, fully coalesced)
        __syncthreads();
        {
            const float4* Ksrc = (const float4*)(Kb + ((size_t)jA << 5));
            const float4* Vsrc = (const float4*)(Vb + ((size_t)jA << 5));
            float4* kd = (float4*)kls;
            float4* vd = (float4*)vls;
            kd[tid]       = Ksrc[tid];
            kd[tid + 256] = Ksrc[tid + 256];
            vd[tid]       = Vsrc[tid];
            vd[tid + 256] = Vsrc[tid + 256];
        }
        __syncthreads();
        unsigned long long mw = msk[((size_t)b * 32 + (jA >> 6)) * SS + row];
        #pragma unroll 2
        for (int jj = 0; jj < 64; jj++) {
            const float* kr = kls + (jj << 5);
            const float* vr = vls + (jj << 5);
            float kv[32];
            #pragma unroll
            for (int i = 0; i < 8; i++)
                *(float4*)(kv + 4*i) = *(const float4*)(kr + 4*i);
            float s0 = 0.f, s1 = 0.f, s2 = 0.f, s3 = 0.f;
            #pragma unroll
            for (int e = 0; e < 8; e++) {
                s0 += ql[e]      * kv[e];
                s1 += ql[8 + e]  * kv[8 + e];
                s2 += ql[16 + e] * kv[16 + e];
                s3 += ql[24 + e] * kv[24 + e];
            }
            bool bit = ((unsigned)(mw >> jj) & 1u) != 0u;
            float w0 = bit ? fexp2(s0) : TINY;
            float w1 = bit ? fexp2(s1) : TINY;
            float w2 = bit ? fexp2(s2) : TINY;
            float w3 = bit ? fexp2(s3) : TINY;
            l[0] += w0; l[1] += w1; l[2] += w2; l[3] += w3;
            float vv[32];
            #pragma unroll
            for (int i = 0; i < 8; i++)
                *(float4*)(vv + 4*i) = *(const float4*)(vr + 4*i);
            #pragma unroll
            for (int e = 0; e < 8; e++) {
                a[e]      += w0 * vv[e];
                a[8 + e]  += w1 * vv[8 + e];
                a[16 + e] += w2 * vv[16 + e];
                a[24 + e] += w3 * vv[24 + e];
            }
        }
    }
    // partial slot: [pn*NCH + jc][36][8192]; k = 0..3 l[h], 4..35 a[h*8+e]
    float* pb = wsf + PART0 + (size_t)(pn * gridDim.x + jc) * PSLOT + grow;
    #pragma unroll
    for (int h = 0; h < 4; h++)
        pb[(size_t)h * 8192] = l[h];
    #pragma unroll
    for (int e = 0; e < 32; e++)
        pb[(size_t)(4 + e) * 8192] = a[e];
}

// ---------- kernel 3a: reduce split-K partials into chunk 0 (per pn) ----------
__global__ __launch_bounds__(256) void k3a_red(float* __restrict__ part, int NCH) {
    int idx = blockIdx.x * 256 + threadIdx.x;   // 147456 float4 slots (2*36*8192/4)
    size_t e = (size_t)idx * 4;
    int pn = (int)(e / PSLOT);
    size_t off = e - (size_t)pn * PSLOT;
    float* base = part + (size_t)pn * NCH * PSLOT + off;
    float4 s = *(const float4*)base;
    for (int c = 1; c < NCH; c++) {
        float4 v = *(const float4*)(base + (size_t)c * PSLOT);
        s.x += v.x; s.y += v.y; s.z += v.z; s.w += v.w;
    }
    *(float4*)base = s;
}

// ---------- kernel 3b: normalize + out-proj + gate (8 rows/block, 32 lanes/row) ----------
__global__ __launch_bounds__(256) void k3b_fin(
    const float* __restrict__ part, int NCH,
    const float* __restrict__ paw, const float* __restrict__ pab,
    const float* __restrict__ naw, const float* __restrict__ nab,
    const float* __restrict__ vpw, const float* __restrict__ vpb,
    const float* __restrict__ vnw, const float* __restrict__ vnb,
    const float* __restrict__ gpw, const float* __restrict__ gpb,
    float* __restrict__ out) {
    __shared__ float sums[8][72];
    __shared__ float Pl[8][64];    // [0..31]=Pp, [32..63]=Pn
    __shared__ float pnv[8][64];   // [0..31]=p,  [32..63]=n
    int tid = threadIdx.x;
    int r = tid >> 5, o = tid & 31;
    int row = blockIdx.x * 8 + r;
    const float* b0 = part + row;                        // pn=0, chunk 0
    const float* b1 = part + (size_t)NCH * PSLOT + row;  // pn=1, chunk 0
    for (int v = o; v < 72; v += 32) {
        int pn = v >= 36;
        int k = v - 36 * pn;
        sums[r][v] = (pn ? b1 : b0)[(size_t)k * 8192];
    }
    __syncthreads();
    // Pp[o] = a_p[o]/l_p[o>>3]; layout: k 0..3 = l, 4..35 = a
    Pl[r][o]      = sums[r][4 + o]  / sums[r][o >> 3];
    Pl[r][32 + o] = sums[r][40 + o] / sums[r][36 + (o >> 3)];
    __syncthreads();
    const float* pw3 = paw + 3*1024; const float* pb3 = pab + 3*32;
    const float* nw3 = naw + 3*1024; const float* nb3 = nab + 3*32;
    float pv = pb3[o], nv = nb3[o];
    #pragma unroll
    for (int d = 0; d < 32; d++) {
        pv += Pl[r][d]      * pw3[o*32 + d];
        nv += Pl[r][32 + d] * nw3[o*32 + d];
    }
    pnv[r][o] = pv; pnv[r][32 + o] = nv;
    __syncthreads();
    float vp = vpb[o], vn = vnb[o], ep = gpb[o], en = gpb[o];
    #pragma unroll
    for (int d = 0; d < 32; d++) {
        float pd = pnv[r][d], nd = pnv[r][32 + d];
        vp += pd * vpw[o*32 + d];
        vn += nd * vnw[o*32 + d];
        ep += pd * gpw[o*32 + d];
        en += nd * gpw[o*32 + d];
    }
    float g = 1.0f / (1.0f + __expf(en - ep));
    out[(size_t)row * 32 + o] = vp * g + vn * (1.0f - g);
}

extern "C" void kernel_launch(void* const* d_in, const int* in_sizes, int n_in,
                              void* d_out, int out_size, void* d_ws, size_t ws_size,
                              hipStream_t stream) {
    const float* feat  = (const float*)d_in[0];
    const float* dmask = (const float*)d_in[1];
    const float* qw  = (const float*)d_in[2];  const float* qb  = (const float*)d_in[3];
    const float* kw  = (const float*)d_in[4];  const float* kb  = (const float*)d_in[5];
    const float* f1w = (const float*)d_in[6];  const float* f1b = (const float*)d_in[7];
    const float* f2w = (const float*)d_in[8];  const float* f2b = (const float*)d_in[9];
    const float* f3w = (const float*)d_in[10]; const float* f3b = (const float*)d_in[11];
    const float* paw = (const float*)d_in[12]; const float* pab = (const float*)d_in[13];
    const float* naw = (const float*)d_in[14]; const float* nab = (const float*)d_in[15];
    const float* vpw = (const float*)d_in[16]; const float* vpb = (const float*)d_in[17];
    const float* vnw = (const float*)d_in[18]; const float* vnb = (const float*)d_in[19];
    const float* gpw = (const float*)d_in[20]; const float* gpb = (const float*)d_in[21];
    float* wsf = (float*)d_ws;
    float* out = (float*)d_out;

    // pick split-K chunk count that fits ws (per chunk: 2 pn x 36*8192 floats)
    size_t avail = ws_size / 4;
    int nch = 1;
    if (avail > (size_t)PART0) {
        size_t per = (size_t)2 * PSLOT;
        size_t m = (avail - PART0) / per;
        nch = (m >= 32) ? 32 : (m >= 16) ? 16 : (m >= 8) ? 8 : (m >= 4) ? 4 :
              (m >= 2) ? 2 : 1;
    }
    int cj = SS / nch;
    float* part = wsf + PART0;

    hipLaunchKernelGGL(k1_proj, dim3(2048), dim3(256), 0, stream,
                       feat, qw, qb, kw, kb, paw, pab, naw, nab, wsf);
    hipLaunchKernelGGL(kA_mask, dim3(8, 32, BB), dim3(256), 0, stream,
                       dmask, wsf, (unsigned long long*)(wsf + MB0),
                       f1w, f1b, f2w, f2b, f3w, f3b);
    hipLaunchKernelGGL(kB_attn, dim3(nch, 8, BB*2), dim3(256), 0, stream,
                       wsf, wsf, cj);
    if (nch > 1)
        hipLaunchKernelGGL(k3a_red, dim3(576), dim3(256), 0, stream, part, nch);
    hipLaunchKernelGGL(k3b_fin, dim3(1024), dim3(256), 0, stream,
                       part, nch, paw, pab, naw, nab, vpw, vpb, vnw, vnb, gpw, gpb,
                       out);
}

// Round 11
// 159.451 us; speedup vs baseline: 1.3264x; 1.3264x over previous
//
#include <hip/hip_runtime.h>
#include <cstddef>

#define BB 4
#define SS 2048
#define DMOD 32
#define AEL (BB*SS*DMOD)            // 262144
#define WS_PROJ 16                  // header (unused)
// ws float-offsets:
//  WS_PROJ + 0*AEL : q_o f32 [8192][32]
//  WS_PROJ + 1*AEL : k_o f32
//  WS_PROJ + 2*AEL : Qbf bf16 [bp=8][2048][32]   (q_p/q_n, *log2e/sqrt8)
//  WS_PROJ + 3*AEL : Kbf bf16 [bp][2048][32]
//  WS_PROJ + 4*AEL : VF  bf16 [bp][512 q][32 col][4 e]  (frag-native V)
#define MB0 (WS_PROJ + 5*AEL)       // pmask (u64 x MWORDS) then nmask
#define MWORDS (BB*32*SS)
#define PART0 (MB0 + 4*MWORDS)
#define PSLOT (36*8192)
#define TINY 1e-30f

typedef __attribute__((ext_vector_type(16))) float f32x16;
typedef __attribute__((ext_vector_type(4)))  short bf16x4;

#if defined(__has_builtin)
#if __has_builtin(__builtin_amdgcn_mfma_f32_32x32x8bf16_1k)
#define HAVE_MFMA328 1
#endif
#endif

__device__ __forceinline__ f32x16 mfma328(bf16x4 a, bf16x4 b, f32x16 c) {
#ifdef HAVE_MFMA328
    return __builtin_amdgcn_mfma_f32_32x32x8bf16_1k(a, b, c, 0, 0, 0);
#else
    f32x16 d;
    asm volatile("v_mfma_f32_32x32x8_bf16 %0, %1, %2, %3\n\t"
                 "s_nop 7\n\t"
                 "s_nop 7\n\t"
                 "s_nop 3"
                 : "=&v"(d) : "v"(a), "v"(b), "v"(c));
    return d;
#endif
}

__device__ __forceinline__ float fexp2(float x) {
#if defined(__has_builtin)
#if __has_builtin(__builtin_amdgcn_exp2f)
    return __builtin_amdgcn_exp2f(x);
#else
    return exp2f(x);
#endif
#else
    return exp2f(x);
#endif
}

// pack two f32 into one dword of 2 bf16 (RNE)
__device__ __forceinline__ unsigned bfpair(float a, float b) {
    unsigned ua = __float_as_uint(a), ub = __float_as_uint(b);
    ua += 0x7fffu + ((ua >> 16) & 1u);
    ub += 0x7fffu + ((ub >> 16) & 1u);
    return (ua >> 16) | (ub & 0xffff0000u);
}

__device__ __forceinline__ bf16x4 packA(float p0, float p1, float p2, float p3) {
    union { unsigned u[2]; bf16x4 v; } c;
    c.u[0] = bfpair(p0, p1);
    c.u[1] = bfpair(p2, p3);
    return c.v;
}

// ---------- kernel 1: projections ----------
// mats: 0 q_o f32, 1 k_o f32, 2 q_p bf16, 3 k_p bf16, 4 v_p VF, 5 q_n, 6 k_n, 7 v_n
__global__ __launch_bounds__(256) void k1_proj(
    const float* __restrict__ feat,
    const float* __restrict__ qw, const float* __restrict__ qb,
    const float* __restrict__ kw, const float* __restrict__ kb,
    const float* __restrict__ paw, const float* __restrict__ pab,
    const float* __restrict__ naw, const float* __restrict__ nab,
    float* __restrict__ wsf) {
    int g = blockIdx.x * 256 + threadIdx.x;
    int d4  = g & 7;
    int mat = (g >> 3) & 7;
    int row = g >> 6;
    const float* W; const float* Bv; float sc = 1.f;
    switch (mat) {
        case 0: W = qw;        Bv = qb;       break;
        case 1: W = kw;        Bv = kb;       break;
        case 2: W = paw;       Bv = pab;      sc = 0.5101370246954918f; break;
        case 3: W = paw+1024;  Bv = pab+32;   break;
        case 4: W = paw+2048;  Bv = pab+64;   break;
        case 5: W = naw;       Bv = nab;      sc = 0.5101370246954918f; break;
        case 6: W = naw+1024;  Bv = nab+32;   break;
        default:W = naw+2048;  Bv = nab+64;   break;
    }
    const float* fr = feat + row * DMOD;
    int o0 = d4 * 4;
    float acc[4];
    #pragma unroll
    for (int i = 0; i < 4; i++) acc[i] = Bv[o0+i];
    #pragma unroll
    for (int d = 0; d < DMOD; d++) {
        float fv = fr[d];
        #pragma unroll
        for (int i = 0; i < 4; i++) acc[i] += fv * W[(o0+i)*DMOD + d];
    }
    #pragma unroll
    for (int i = 0; i < 4; i++) acc[i] *= sc;

    if (mat < 2) {
        float4 r = make_float4(acc[0], acc[1], acc[2], acc[3]);
        *(float4*)(wsf + WS_PROJ + (size_t)mat*AEL + (size_t)row*DMOD + o0) = r;
        return;
    }
    int b = row >> 11, r2 = row & 2047;
    int pn = (mat >= 5);
    int bp = (b << 1) | pn;
    int m3 = mat - (pn ? 5 : 2);     // 0=q,1=k,2=v
    unsigned lo  = bfpair(acc[0], acc[1]);
    unsigned hi2 = bfpair(acc[2], acc[3]);
    if (m3 == 0) {
        unsigned* dst = (unsigned*)((unsigned short*)(wsf + WS_PROJ + 2*(size_t)AEL)
                         + (size_t)bp*65536 + (size_t)r2*32 + o0);
        dst[0] = lo; dst[1] = hi2;
    } else if (m3 == 1) {
        unsigned* dst = (unsigned*)((unsigned short*)(wsf + WS_PROJ + 3*(size_t)AEL)
                         + (size_t)bp*65536 + (size_t)r2*32 + o0);
        dst[0] = lo; dst[1] = hi2;
    } else {
        unsigned short* vf = (unsigned short*)(wsf + WS_PROJ + 4*(size_t)AEL)
                         + (size_t)bp*65536 + (size_t)(r2>>2)*128 + (r2&3);
        vf[(size_t)(o0+0)*4] = (unsigned short)(lo & 0xffffu);
        vf[(size_t)(o0+1)*4] = (unsigned short)(lo >> 16);
        vf[(size_t)(o0+2)*4] = (unsigned short)(hi2 & 0xffffu);
        vf[(size_t)(o0+3)*4] = (unsigned short)(hi2 >> 16);
    }
}

// ---------- kernel A: fused-score sign bits -> packed p/n masks (unchanged) ----------
__global__ __launch_bounds__(256) void kA_mask(
    const float* __restrict__ dmask, const float* __restrict__ proj,
    unsigned long long* __restrict__ pmout,
    const float* __restrict__ f1w, const float* __restrict__ f1b,
    const float* __restrict__ f2w, const float* __restrict__ f2b,
    const float* __restrict__ f3w, const float* __restrict__ f3b) {
    int tid = threadIdx.x;
    int w = tid >> 6, lane = tid & 63;
    int jt = blockIdx.x, rt = blockIdx.y, b = blockIdx.z;
    int jg = jt * 256 + w * 64 + lane;
    float cc[4];
    #pragma unroll
    for (int h = 0; h < 4; h++) {
        float s = 0.f;
        #pragma unroll
        for (int a = 0; a < 4; a++) {
            float t = 0.f;
            #pragma unroll
            for (int bb = 0; bb < 8; bb++) t += f2w[a*8+bb] * f1w[bb*4+h];
            s += f3w[a] * t;
        }
        cc[h] = s * 0.35355339059327373f;
    }
    float cbv = f3b[0];
    #pragma unroll
    for (int a = 0; a < 4; a++) {
        float t = f2b[a];
        #pragma unroll
        for (int bb = 0; bb < 8; bb++) t += f2w[a*8+bb] * f1b[bb];
        cbv += f3w[a] * t;
    }
    const float* KOb = proj + WS_PROJ + 1*(size_t)AEL + ((size_t)b*SS + jg) * DMOD;
    float ko[32];
    #pragma unroll
    for (int i = 0; i < 8; i++) {
        float4 v = *(const float4*)(KOb + 4*i);
        ko[4*i] = v.x; ko[4*i+1] = v.y; ko[4*i+2] = v.z; ko[4*i+3] = v.w;
    }
    const float* QOb = proj + WS_PROJ + 0*(size_t)AEL + (size_t)b*SS*DMOD;
    unsigned long long* pm = pmout;
    unsigned long long* nm = pmout + MWORDS;
    const float* dmr = dmask + (size_t)b * SS * SS + jg;
    int j64 = jt * 4 + w;
    size_t mbase = ((size_t)b * 32 + j64) * SS;
    #pragma unroll 8
    for (int r = 0; r < 64; r++) {
        int row = rt * 64 + r;
        const float* qr = QOb + (size_t)row * DMOD;
        float dm = dmr[(size_t)row * SS];
        float fa = 0.f, fb = 0.f, fc = 0.f, fd = 0.f;
        #pragma unroll
        for (int d = 0; d < 8; d++) {
            fa += qr[d]      * ko[d];
            fb += qr[8 + d]  * ko[8 + d];
            fc += qr[16 + d] * ko[16 + d];
            fd += qr[24 + d] * ko[24 + d];
        }
        float fused = cbv + cc[0]*fa + cc[1]*fb + cc[2]*fc + cc[3]*fd;
        bool act = (dm != 0.0f);
        unsigned long long bp = __ballot(act && (fused > 0.0f));
        unsigned long long bn = __ballot(act && !(fused > 0.0f));
        if (lane == 0) {
            pm[mbase + row] = bp;
            nm[mbase + row] = bn;
        }
    }
}

// ---------- kernel B: MFMA masked attention (p or n), split-K ----------
// grid (nch, 16, 8): bp = blockIdx.z (b<<1|pn); block 256 = 4 waves, wave = 32-row tile
__global__ __launch_bounds__(256) void kB_attn(
    const unsigned short* __restrict__ qbf,
    const unsigned short* __restrict__ kbf,
    const unsigned short* __restrict__ vff,
    const unsigned long long* __restrict__ mall,
    float* __restrict__ part, int CJ, int NCH) {
    int tid = threadIdx.x;
    int w = tid >> 6, l = tid & 63, li = l & 31, hi = l >> 5;
    int jc = blockIdx.x, rg = blockIdx.y, bp = blockIdx.z;
    int b = bp >> 1, pn = bp & 1;
    int it32 = rg * 128 + w * 32;

    // Q B-fragments (per head): B[k=4*hi+e][col=li] = Q[it32+li][h*8 + 4*hi + e]
    const unsigned short* qrow = qbf + (size_t)bp*65536 + (size_t)(it32 + li)*32 + 4*hi;
    bf16x4 qf[4];
    #pragma unroll
    for (int h = 0; h < 4; h++) qf[h] = *(const bf16x4*)(qrow + h*8);

    const unsigned short* kbase = kbf + (size_t)bp*65536 + (size_t)li*32 + 4*hi;
    const unsigned short* vbase = vff + (size_t)bp*65536 + (size_t)hi*128;
    const unsigned long long* msk = mall + (size_t)pn*MWORDS
                                   + (size_t)b*32*SS + (it32 + li);

    f32x16 zero16;
    #pragma unroll
    for (int r = 0; r < 16; r++) zero16[r] = 0.f;
    f32x16 oacc[4];
    #pragma unroll
    for (int h = 0; h < 4; h++)
        #pragma unroll
        for (int r = 0; r < 16; r++) oacc[h][r] = 0.f;
    float lsum[4] = {0.f, 0.f, 0.f, 0.f};

    int j0 = jc * CJ;
    for (int jw = 0; jw < CJ; jw += 64) {
        unsigned long long mw = msk[(size_t)((j0 + jw) >> 6) * SS];
        #pragma unroll
        for (int half = 0; half < 2; half++) {
            int jt = j0 + jw + half*32;
            unsigned m32 = (unsigned)(mw >> (half*32));
            const unsigned short* krow = kbase + (size_t)jt*32;
            const unsigned short* vrow = vbase + (size_t)(jt>>2)*128;
            #pragma unroll
            for (int h = 0; h < 4; h++) {
                bf16x4 kf = *(const bf16x4*)(krow + h*8);
                int vcol = ((h*8 + li) & 31) * 4;
                bf16x4 vf0 = *(const bf16x4*)(vrow + 0*256 + vcol);
                bf16x4 vf1 = *(const bf16x4*)(vrow + 1*256 + vcol);
                bf16x4 vf2 = *(const bf16x4*)(vrow + 2*256 + vcol);
                bf16x4 vf3 = *(const bf16x4*)(vrow + 3*256 + vcol);
                // S^T tile = K_tile · Q_tile^T : lane owns query i=it32+li (col),
                // key rows j via regs: j = jt + (r&3)+8*(r>>2)+4*hi
                f32x16 sacc = mfma328(kf, qf[h], zero16);
                float p[16];
                #pragma unroll
                for (int r = 0; r < 16; r++) {
                    int sh = (r & 3) + 8*(r >> 2);
                    unsigned bit = (m32 >> (sh + 4*hi)) & 1u;
                    float e = fexp2(sacc[r]);
                    p[r] = bit ? e : TINY;
                    lsum[h] += p[r];
                }
                // P chunks are A-fragment-ordered: regs 4c..4c+3 = keys jt+8c+4hi+e
                oacc[h] = mfma328(packA(p[0],  p[1],  p[2],  p[3]),  vf0, oacc[h]);
                oacc[h] = mfma328(packA(p[4],  p[5],  p[6],  p[7]),  vf1, oacc[h]);
                oacc[h] = mfma328(packA(p[8],  p[9],  p[10], p[11]), vf2, oacc[h]);
                oacc[h] = mfma328(packA(p[12], p[13], p[14], p[15]), vf3, oacc[h]);
            }
        }
    }
    // epilogue: partial slot [pn*NCH+jc][36][8192]; k: 0..3 l[h], 4..35 a[h*8+d]
    float* base2 = part + (size_t)(pn * NCH + jc) * PSLOT + (size_t)b * SS;
    #pragma unroll
    for (int h = 0; h < 4; h++) {
        float lt = lsum[h] + __shfl_xor(lsum[h], 32);
        if (hi == 0) base2[(size_t)h * 8192 + it32 + li] = lt;
    }
    if (li < 8) {
        #pragma unroll
        for (int h = 0; h < 4; h++) {
            #pragma unroll
            for (int r = 0; r < 16; r++) {
                int irow = it32 + (r & 3) + 8*(r >> 2) + 4*hi;
                base2[(size_t)(4 + h*8 + li) * 8192 + irow] = oacc[h][r];
            }
        }
    }
}

// ---------- kernel 3a: reduce split-K partials into chunk 0 (per pn) ----------
__global__ __launch_bounds__(256) void k3a_red(float* __restrict__ part, int NCH) {
    int idx = blockIdx.x * 256 + threadIdx.x;
    size_t e = (size_t)idx * 4;
    int pn = (int)(e / PSLOT);
    size_t off = e - (size_t)pn * PSLOT;
    float* base = part + (size_t)pn * NCH * PSLOT + off;
    float4 s = *(const float4*)base;
    for (int c = 1; c < NCH; c++) {
        float4 v = *(const float4*)(base + (size_t)c * PSLOT);
        s.x += v.x; s.y += v.y; s.z += v.z; s.w += v.w;
    }
    *(float4*)base = s;
}

// ---------- kernel 3b: normalize + out-proj + gate ----------
__global__ __launch_bounds__(256) void k3b_fin(
    const float* __restrict__ part, int NCH,
    const float* __restrict__ paw, const float* __restrict__ pab,
    const float* __restrict__ naw, const float* __restrict__ nab,
    const float* __restrict__ vpw, const float* __restrict__ vpb,
    const float* __restrict__ vnw, const float* __restrict__ vnb,
    const float* __restrict__ gpw, const float* __restrict__ gpb,
    float* __restrict__ out) {
    __shared__ float sums[8][72];
    __shared__ float Pl[8][64];
    __shared__ float pnv[8][64];
    int tid = threadIdx.x;
    int r = tid >> 5, o = tid & 31;
    int row = blockIdx.x * 8 + r;
    const float* b0 = part + row;
    const float* b1 = part + (size_t)NCH * PSLOT + row;
    for (int v = o; v < 72; v += 32) {
        int pn = v >= 36;
        int k = v - 36 * pn;
        sums[r][v] = (pn ? b1 : b0)[(size_t)k * 8192];
    }
    __syncthreads();
    Pl[r][o]      = sums[r][4 + o]  / sums[r][o >> 3];
    Pl[r][32 + o] = sums[r][40 + o] / sums[r][36 + (o >> 3)];
    __syncthreads();
    const float* pw3 = paw + 3*1024; const float* pb3 = pab + 3*32;
    const float* nw3 = naw + 3*1024; const float* nb3 = nab + 3*32;
    float pv = pb3[o], nv = nb3[o];
    #pragma unroll
    for (int d = 0; d < 32; d++) {
        pv += Pl[r][d]      * pw3[o*32 + d];
        nv += Pl[r][32 + d] * nw3[o*32 + d];
    }
    pnv[r][o] = pv; pnv[r][32 + o] = nv;
    __syncthreads();
    float vp = vpb[o], vn = vnb[o], ep = gpb[o], en = gpb[o];
    #pragma unroll
    for (int d = 0; d < 32; d++) {
        float pd = pnv[r][d], nd = pnv[r][32 + d];
        vp += pd * vpw[o*32 + d];
        vn += nd * vnw[o*32 + d];
        ep += pd * gpw[o*32 + d];
        en += nd * gpw[o*32 + d];
    }
    float g = 1.0f / (1.0f + __expf(en - ep));
    out[(size_t)row * 32 + o] = vp * g + vn * (1.0f - g);
}

extern "C" void kernel_launch(void* const* d_in, const int* in_sizes, int n_in,
                              void* d_out, int out_size, void* d_ws, size_t ws_size,
                              hipStream_t stream) {
    const float* feat  = (const float*)d_in[0];
    const float* dmask = (const float*)d_in[1];
    const float* qw  = (const float*)d_in[2];  const float* qb  = (const float*)d_in[3];
    const float* kw  = (const float*)d_in[4];  const float* kb  = (const float*)d_in[5];
    const float* f1w = (const float*)d_in[6];  const float* f1b = (const float*)d_in[7];
    const float* f2w = (const float*)d_in[8];  const float* f2b = (const float*)d_in[9];
    const float* f3w = (const float*)d_in[10]; const float* f3b = (const float*)d_in[11];
    const float* paw = (const float*)d_in[12]; const float* pab = (const float*)d_in[13];
    const float* naw = (const float*)d_in[14]; const float* nab = (const float*)d_in[15];
    const float* vpw = (const float*)d_in[16]; const float* vpb = (const float*)d_in[17];
    const float* vnw = (const float*)d_in[18]; const float* vnb = (const float*)d_in[19];
    const float* gpw = (const float*)d_in[20]; const float* gpb = (const float*)d_in[21];
    float* wsf = (float*)d_ws;
    float* out = (float*)d_out;

    size_t avail = ws_size / 4;
    int nch = 1;
    if (avail > (size_t)PART0) {
        size_t per = (size_t)2 * PSLOT;
        size_t m = (avail - PART0) / per;
        nch = (m >= 8) ? 8 : (m >= 4) ? 4 : (m >= 2) ? 2 : 1;
    }
    int cj = SS / nch;
    float* part = wsf + PART0;

    const unsigned short* qbfu = (const unsigned short*)(wsf + WS_PROJ + 2*(size_t)AEL);
    const unsigned short* kbfu = (const unsigned short*)(wsf + WS_PROJ + 3*(size_t)AEL);
    const unsigned short* vffu = (const unsigned short*)(wsf + WS_PROJ + 4*(size_t)AEL);

    hipLaunchKernelGGL(k1_proj, dim3(2048), dim3(256), 0, stream,
                       feat, qw, qb, kw, kb, paw, pab, naw, nab, wsf);
    hipLaunchKernelGGL(kA_mask, dim3(8, 32, BB), dim3(256), 0, stream,
                       dmask, wsf, (unsigned long long*)(wsf + MB0),
                       f1w, f1b, f2w, f2b, f3w, f3b);
    hipLaunchKernelGGL(kB_attn, dim3(nch, 16, BB*2), dim3(256), 0, stream,
                       qbfu, kbfu, vffu,
                       (const unsigned long long*)(wsf + MB0), part, cj, nch);
    if (nch > 1)
        hipLaunchKernelGGL(k3a_red, dim3(576), dim3(256), 0, stream, part, nch);
    hipLaunchKernelGGL(k3b_fin, dim3(1024), dim3(256), 0, stream,
                       part, nch, paw, pab, naw, nab, vpw, vpb, vnw, vnb, gpw, gpb,
                       out);
}